// Round 1
// baseline (334.633 us; speedup 1.0000x reference)
//
#include <hip/hip_runtime.h>
#include <hip/hip_bf16.h>

// GINE on MI355X — fp32 inputs/outputs; bf16 MFMA internals.
static const int NN = 100000;   // nodes
static const int NE = 1600000;  // edges
static const int NG = 512;      // graphs
static const int NB = 391;      // coarse buckets of 256 nodes (dst >> 8)
static const int PS = 4608;     // pairs region per bucket (mean 4096 + 8 sigma)
static const int CS = 4624;     // csr region per bucket (PS + 16 zero-fill slack)

typedef __attribute__((ext_vector_type(8))) short shortx8;
typedef __attribute__((ext_vector_type(4))) float floatx4;
typedef __attribute__((ext_vector_type(2))) float floatx2;

__device__ __forceinline__ float bf2f(unsigned short u) {
  union { unsigned int i; float f; } v; v.i = ((unsigned int)u) << 16; return v.f;
}
__device__ __forceinline__ unsigned short f2bf(float f) {
  union { float f; unsigned int i; } v; v.f = f;
  return (unsigned short)((v.i + 0x7FFFu + ((v.i >> 16) & 1u)) >> 16);
}
__device__ __forceinline__ float elu_fast(float v) {
  return v > 0.f ? v : (__builtin_amdgcn_exp2f(v * 1.44269504f) - 1.f);
}
// unpack packed 2x bf16 -> float2 (2 VALU: shl, and)
__device__ __forceinline__ floatx2 unpk(unsigned int v) {
  union { unsigned int i; float f; } a, b;
  a.i = v << 16; b.i = v & 0xFFFF0000u;
  floatx2 r; r.x = a.f; r.y = b.f; return r;
}

// ---- one prep kernel ----------------------------------------------------
// blocks 0..7: et1 | 8..483: M0 (bf16) | 484..867: weight swizzle |
// 868..883: zero hgf | 884: bcursor init.
__global__ void k_prep(const float* __restrict__ bond,
                       const float* __restrict__ we0, const float* __restrict__ be0,
                       const float* __restrict__ we1, const float* __restrict__ be1,
                       const float* __restrict__ atom,
                       float* __restrict__ et1, unsigned short* __restrict__ M0,
                       float* __restrict__ hgf, int* __restrict__ bcursor,
                       const float* __restrict__ s0, const float* __restrict__ s1,
                       const float* __restrict__ s2, const float* __restrict__ s3,
                       const float* __restrict__ s4, const float* __restrict__ s5,
                       unsigned short* __restrict__ d0, unsigned short* __restrict__ d1,
                       unsigned short* __restrict__ d2, unsigned short* __restrict__ d3,
                       unsigned short* __restrict__ d4, unsigned short* __restrict__ d5) {
  int blk = blockIdx.x, t = threadIdx.x;
  if (blk < 8) {                      // et1[16][128] = bond@we1 + be1
    int i = blk * 256 + t;
    int b = i >> 7, c = i & 127;
    float acc = be1[c];
    for (int k = 0; k < 64; ++k) acc += bond[b * 64 + k] * we1[k * 128 + c];
    et1[i] = acc;
  } else if (blk < 484) {             // M0 (bf16) = relu(atom + bond@we0 + be0)
    int i = (blk - 8) * 256 + t;      // 476*256 == 119*16*64
    int c = i & 63, b = (i >> 6) & 15, a = i >> 10;
    float acc = be0[c];
    for (int k = 0; k < 64; ++k) acc += bond[b * 64 + k] * we0[k * 64 + c];
    acc += atom[a * 64 + c];
    M0[i] = f2bf(acc > 0.f ? acc : 0.f);
  } else if (blk < 868) {             // weight swizzle into MFMA B-frag order
    int task = (blk - 484) >> 6;
    int i = ((blk - 484) & 63) * 256 + t;
    const float* w; unsigned short* wz; int K;
    switch (task) {
      case 0: w = s0; wz = d0; K = 64; break;
      case 1: w = s1; wz = d1; K = 128; break;
      case 2: w = s2; wz = d2; K = 128; break;
      case 3: w = s3; wz = d3; K = 128; break;
      case 4: w = s4; wz = d4; K = 128; break;
      default: w = s5; wz = d5; K = 128; break;
    }
    if (i >= K * 128) return;
    int j = i & 7, lane = (i >> 3) & 63, ct = (i >> 9) & 7, s = i >> 12;
    int k = s * 32 + (lane >> 4) * 8 + j;
    int m = ct * 16 + (lane & 15);
    wz[i] = f2bf(w[k * 128 + m]);
  } else if (blk < 884) {             // zero hgf (512*128 floats)
    int base = (blk - 868) * 4096;
#pragma unroll
    for (int k = 0; k < 16; ++k) hgf[base + k * 256 + t] = 0.f;
  } else {                            // bcursor fixed bases
    if (t < NB) bcursor[t] = t * PS;
    int u = t + 256;
    if (u < NB) bcursor[u] = u * PS;
  }
}

// Pass B: bin 4096-edge chunks by coarse bucket into fixed per-bucket regions.
__global__ void k_bin(const int* __restrict__ src, const int* __restrict__ dstp,
                      const int* __restrict__ ea, const int* __restrict__ x_idx,
                      int* __restrict__ bcursor, uint2* __restrict__ pairs) {
  __shared__ int cnt[512];
  __shared__ int incl[512];
  __shared__ int cur[NB];
  __shared__ int rbase[NB];
  __shared__ uint2 stage[4096];
  int t = threadIdx.x;
  int e0 = blockIdx.x * 4096;
  int ecnt = NE - e0; if (ecnt > 4096) ecnt = 4096;
  cnt[t] = 0; cnt[t + 256] = 0;
  __syncthreads();
  for (int k = 0; k < 16; ++k) {
    int i = k * 256 + t;
    if (i < ecnt) atomicAdd(&cnt[dstp[e0 + i] >> 8], 1);
  }
  __syncthreads();
  incl[t] = cnt[t]; incl[t + 256] = cnt[t + 256];
  __syncthreads();
  for (int d = 1; d < 512; d <<= 1) {
    int v0 = (t >= d) ? incl[t - d] : 0;
    int v1 = (t + 256 >= d) ? incl[t + 256 - d] : 0;
    __syncthreads();
    incl[t] += v0; incl[t + 256] += v1;
    __syncthreads();
  }
  if (t < NB) { cur[t] = incl[t] - cnt[t]; if (cnt[t]) rbase[t] = atomicAdd(&bcursor[t], cnt[t]); }
  int u = t + 256;
  if (u < NB) { cur[u] = incl[u] - cnt[u]; if (cnt[u]) rbase[u] = atomicAdd(&bcursor[u], cnt[u]); }
  __syncthreads();
  for (int k = 0; k < 16; ++k) {
    int i = k * 256 + t;
    if (i < ecnt) {
      int e = e0 + i;
      int d = dstp[e];
      int s = src[e];
      unsigned int pk = (unsigned int)s | ((unsigned int)(x_idx[s] * 16 + ea[e]) << 17);
      int p = atomicAdd(&cur[d >> 8], 1);
      stage[p] = make_uint2((unsigned int)d, pk);
    }
  }
  __syncthreads();
  for (int j = t; j < ecnt; j += 256) {   // bucket from dst — no search
    uint2 p = stage[j];
    int b = (int)(p.x >> 8);
    int excl = incl[b] - cnt[b];
    pairs[rbase[b] + (j - excl)] = p;
  }
}

// Pass C: fine counting-sort per bucket; absolute offs + cnts; 16 zero slots.
//   csr0[i] = M0-row byte offset (bf16 rows: idx17*128)
//   csr1[i] = (src*256) | bond
__global__ void k_fine(const uint2* __restrict__ pairs, const int* __restrict__ bcursor,
                       int* __restrict__ offs, int* __restrict__ cnts,
                       unsigned int* __restrict__ csr0, unsigned int* __restrict__ csr1) {
  __shared__ int cnt[256];
  __shared__ int incl[256];
  __shared__ int cur[256];
  int b = blockIdx.x;
  int t = threadIdx.x;
  int start = b * PS;
  int endv = bcursor[b];
  int cbase = b * CS;
  int base_n = b << 8;
  cnt[t] = 0;
  __syncthreads();
  for (int j = start + t; j < endv; j += 256)
    atomicAdd(&cnt[(int)pairs[j].x - base_n], 1);
  __syncthreads();
  incl[t] = cnt[t];
  __syncthreads();
  for (int d = 1; d < 256; d <<= 1) {
    int v = (t >= d) ? incl[t - d] : 0;
    __syncthreads();
    incl[t] += v;
    __syncthreads();
  }
  int excl = incl[t] - cnt[t];
  cur[t] = excl;
  int node = base_n + t;
  if (node < NN) { offs[node] = cbase + excl; cnts[node] = cnt[t]; }
  __syncthreads();
  for (int j = start + t; j < endv; j += 256) {
    uint2 p = pairs[j];
    int pos = cbase + atomicAdd(&cur[(int)p.x - base_n], 1);
    unsigned int pk = p.y;
    unsigned int idx17 = pk >> 17;
    csr0[pos] = idx17 << 7;                 // bf16 M0 rows: 128 B
    csr1[pos] = ((pk & 0x1FFFFu) << 8) | (idx17 & 15u);
  }
  __syncthreads();
  int total = incl[255];
  if (t < 16) { csr0[cbase + total + t] = 0u; csr1[cbase + total + t] = 0u; }
}

// ---- aggregation layer 0: wave per node; EIGHTH-wave per edge.
// 8 lanes x dwordx4 = one 128 B M0 row; 8 edges per gather instruction.
// Final cross-octet merge: shfl_xor butterfly (8/16/32).
__global__ __launch_bounds__(256) void k_agg0(
    const int* __restrict__ x_idx, const float* __restrict__ atom,
    const unsigned short* __restrict__ M0, const int* __restrict__ offs,
    const int* __restrict__ cnts,
    const unsigned int* __restrict__ csr0, unsigned short* __restrict__ h0) {
  int t = threadIdx.x, lane = t & 63;
  int oct = lane >> 3, cl = lane & 7;      // edge slot / channel-octet lane
  int n = __builtin_amdgcn_readfirstlane(blockIdx.x * 4 + (t >> 6));
  if (n >= NN) return;
  int s = offs[n], e = s + cnts[n];
  const char* Mb = (const char*)M0;
  unsigned int claneoff = (unsigned int)(cl * 16);   // bits [6:4], row offs bits >=7
  floatx2 a0, a1, a2, a3;                  // 8 channels: 8*cl .. 8*cl+7
  a0.x = a0.y = a1.x = a1.y = a2.x = a2.y = a3.x = a3.y = 0.f;
  if (oct == 0) {                          // self term: x (atom row, fp32)
    const float* ap = atom + ((size_t)(unsigned)x_idx[n] << 6) + (cl << 3);
    float4 f0 = *(const float4*)ap;
    float4 f1 = *(const float4*)(ap + 4);
    a0.x = f0.x; a0.y = f0.y; a1.x = f0.z; a1.y = f0.w;
    a2.x = f1.x; a2.y = f1.y; a3.x = f1.z; a3.y = f1.w;
  }
  const unsigned int* cp = csr0 + s + oct;
  for (int r = e - s; r > 0; r -= 16, cp += 16) {
    unsigned int qA = cp[0];               // edge s.. + oct
    unsigned int qB = cp[8];               // edge s.. + 8 + oct
    float mA = (oct < r) ? 1.f : 0.f;
    float mB = (oct + 8 < r) ? 1.f : 0.f;
    floatx2 mA2; mA2.x = mA; mA2.y = mA;
    floatx2 mB2; mB2.x = mB; mB2.y = mB;
    uint4 vA = *(const uint4*)(Mb + (size_t)(qA | claneoff));
    uint4 vB = *(const uint4*)(Mb + (size_t)(qB | claneoff));
    a0 = __builtin_elementwise_fma(mA2, unpk(vA.x), a0);
    a1 = __builtin_elementwise_fma(mA2, unpk(vA.y), a1);
    a2 = __builtin_elementwise_fma(mA2, unpk(vA.z), a2);
    a3 = __builtin_elementwise_fma(mA2, unpk(vA.w), a3);
    a0 = __builtin_elementwise_fma(mB2, unpk(vB.x), a0);
    a1 = __builtin_elementwise_fma(mB2, unpk(vB.y), a1);
    a2 = __builtin_elementwise_fma(mB2, unpk(vB.z), a2);
    a3 = __builtin_elementwise_fma(mB2, unpk(vB.w), a3);
  }
  // reduce across 8 octets (lane bits 3,4,5)
  a0.x += __shfl_xor(a0.x, 8);  a0.y += __shfl_xor(a0.y, 8);
  a1.x += __shfl_xor(a1.x, 8);  a1.y += __shfl_xor(a1.y, 8);
  a2.x += __shfl_xor(a2.x, 8);  a2.y += __shfl_xor(a2.y, 8);
  a3.x += __shfl_xor(a3.x, 8);  a3.y += __shfl_xor(a3.y, 8);
  a0.x += __shfl_xor(a0.x, 16); a0.y += __shfl_xor(a0.y, 16);
  a1.x += __shfl_xor(a1.x, 16); a1.y += __shfl_xor(a1.y, 16);
  a2.x += __shfl_xor(a2.x, 16); a2.y += __shfl_xor(a2.y, 16);
  a3.x += __shfl_xor(a3.x, 16); a3.y += __shfl_xor(a3.y, 16);
  a0.x += __shfl_xor(a0.x, 32); a0.y += __shfl_xor(a0.y, 32);
  a1.x += __shfl_xor(a1.x, 32); a1.y += __shfl_xor(a1.y, 32);
  a2.x += __shfl_xor(a2.x, 32); a2.y += __shfl_xor(a2.y, 32);
  a3.x += __shfl_xor(a3.x, 32); a3.y += __shfl_xor(a3.y, 32);
  if (oct == 0) {
    uint4 o;
    o.x = (unsigned int)f2bf(a0.x) | ((unsigned int)f2bf(a0.y) << 16);
    o.y = (unsigned int)f2bf(a1.x) | ((unsigned int)f2bf(a1.y) << 16);
    o.z = (unsigned int)f2bf(a2.x) | ((unsigned int)f2bf(a2.y) << 16);
    o.w = (unsigned int)f2bf(a3.x) | ((unsigned int)f2bf(a3.y) << 16);
    *(uint4*)((char*)h0 + ((size_t)n << 7) + claneoff) = o;
  }
}

// ---- aggregation layer 1 edge update: 16 lanes x dwordx4 = one 256 B x1 row.
// et read from bank-swizzled LDS (140-word rows, +4*(c>>5) word shift):
// the 16 chunk starts land on 8 distinct bank positions x 2 lanes = conflict-free.
__device__ __forceinline__ void upd1(unsigned int q, float m,
    const char* xb, const char* etb, unsigned int claneoff,
    floatx2& a0, floatx2& a1, floatx2& a2, floatx2& a3) {
  floatx2 mm; mm.x = m; mm.y = m;
  floatx2 z2; z2.x = 0.f; z2.y = 0.f;
  uint4 v = *(const uint4*)(xb + (size_t)((q & 0xFFFFFF00u) | claneoff));
  const char* ee = etb + (q & 15u) * 560u;      // 140 words * 4 B per et row
  floatx4 ef0 = *(const floatx4*)(ee);
  floatx4 ef1 = *(const floatx4*)(ee + 16);
  floatx2 e0; e0.x = ef0.x; e0.y = ef0.y;
  floatx2 e1; e1.x = ef0.z; e1.y = ef0.w;
  floatx2 e2; e2.x = ef1.x; e2.y = ef1.y;
  floatx2 e3; e3.x = ef1.z; e3.y = ef1.w;
  a0 = __builtin_elementwise_fma(mm, __builtin_elementwise_max(unpk(v.x) + e0, z2), a0);
  a1 = __builtin_elementwise_fma(mm, __builtin_elementwise_max(unpk(v.y) + e1, z2), a1);
  a2 = __builtin_elementwise_fma(mm, __builtin_elementwise_max(unpk(v.z) + e2, z2), a2);
  a3 = __builtin_elementwise_fma(mm, __builtin_elementwise_max(unpk(v.w) + e3, z2), a3);
}

// ---- aggregation layer 1: wave per node; QUARTER-wave per edge.
// 16 lanes x dwordx4 = one 256 B x1 row; 4 edges per gather instruction.
__global__ __launch_bounds__(256) void k_agg1(
    const unsigned short* __restrict__ x1, const float* __restrict__ et1,
    const int* __restrict__ offs, const int* __restrict__ cnts,
    const unsigned int* __restrict__ csr1, unsigned short* __restrict__ h1) {
  __shared__ float etl[16 * 140];          // swizzled 16 rows x 128 ch, 8.75 KB
  int t = threadIdx.x;
#pragma unroll
  for (int k = 0; k < 8; ++k) {
    int idx = k * 256 + t;
    int b = idx >> 7, c = idx & 127;
    etl[b * 140 + c + ((c >> 5) << 2)] = et1[idx];
  }
  __syncthreads();
  int lane = t & 63;
  int qtr = lane >> 4, cl = lane & 15;     // edge slot / channel-16th lane
  int n = __builtin_amdgcn_readfirstlane(blockIdx.x * 4 + (t >> 6));
  if (n >= NN) return;
  int s = offs[n], e = s + cnts[n];
  const char* xb = (const char*)x1;
  const char* etb = (const char*)etl + (size_t)(cl * 32 + ((cl >> 2) << 4));
  unsigned int claneoff = (unsigned int)(cl * 16);   // bits [7:4], row offs bits >=8
  floatx2 a0, a1, a2, a3;                  // 8 channels: 8*cl .. 8*cl+7
  a0.x = a0.y = a1.x = a1.y = a2.x = a2.y = a3.x = a3.y = 0.f;
  if (qtr == 0) {                          // self term: h = x + agg
    uint4 v = *(const uint4*)(xb + ((size_t)(unsigned)n << 8) + claneoff);
    a0 = unpk(v.x); a1 = unpk(v.y); a2 = unpk(v.z); a3 = unpk(v.w);
  }
  const unsigned int* cp = csr1 + s + qtr;
  for (int r = e - s; r > 0; r -= 8, cp += 8) {
    unsigned int qA = cp[0];               // edge s.. + qtr
    unsigned int qB = cp[4];               // edge s.. + 4 + qtr
    float mA = (qtr < r) ? 1.f : 0.f;
    float mB = (qtr + 4 < r) ? 1.f : 0.f;
    upd1(qA, mA, xb, etb, claneoff, a0, a1, a2, a3);
    upd1(qB, mB, xb, etb, claneoff, a0, a1, a2, a3);
  }
  // reduce across 4 quarters (lane bits 4,5)
  a0.x += __shfl_xor(a0.x, 16); a0.y += __shfl_xor(a0.y, 16);
  a1.x += __shfl_xor(a1.x, 16); a1.y += __shfl_xor(a1.y, 16);
  a2.x += __shfl_xor(a2.x, 16); a2.y += __shfl_xor(a2.y, 16);
  a3.x += __shfl_xor(a3.x, 16); a3.y += __shfl_xor(a3.y, 16);
  a0.x += __shfl_xor(a0.x, 32); a0.y += __shfl_xor(a0.y, 32);
  a1.x += __shfl_xor(a1.x, 32); a1.y += __shfl_xor(a1.y, 32);
  a2.x += __shfl_xor(a2.x, 32); a2.y += __shfl_xor(a2.y, 32);
  a3.x += __shfl_xor(a3.x, 32); a3.y += __shfl_xor(a3.y, 32);
  if (qtr == 0) {
    uint4 o;
    o.x = (unsigned int)f2bf(a0.x) | ((unsigned int)f2bf(a0.y) << 16);
    o.y = (unsigned int)f2bf(a1.x) | ((unsigned int)f2bf(a1.y) << 16);
    o.z = (unsigned int)f2bf(a2.x) | ((unsigned int)f2bf(a2.y) << 16);
    o.w = (unsigned int)f2bf(a3.x) | ((unsigned int)f2bf(a3.y) << 16);
    *(uint4*)((char*)h1 + ((size_t)n << 8) + claneoff) = o;
  }
}

// ---- double-GEMM MLP: 128 rows/block (2 tiles), w2 in LDS, one barrier,
// wave-private tls, coalesced dwordx4 stores.
template <int K1>
__global__ __launch_bounds__(256) void k_mlp_t(
    const unsigned short* __restrict__ in,
    const unsigned short* __restrict__ w1z, const float* __restrict__ b1,
    const unsigned short* __restrict__ w2z, const float* __restrict__ b2,
    unsigned short* __restrict__ outb, int N) {
  __shared__ unsigned short tls[4][16][136];   // wave-private mid/out tile
  __shared__ unsigned short b2s[16384];        // 32 KB staged w2 frags
  int t = threadIdx.x;
  int lane = t & 63;
  int wave = t >> 6;
  int rlo = lane & 15, quad = lane >> 4;

#pragma unroll
  for (int k = 0; k < 8; ++k)
    *(shortx8*)&b2s[(k * 256 + t) * 8] = *(const shortx8*)&w2z[(k * 256 + t) * 8];

  float bm1[8], bm2[8];
#pragma unroll
  for (int ct = 0; ct < 8; ++ct) { bm1[ct] = b1[ct * 16 + rlo]; bm2[ct] = b2[ct * 16 + rlo]; }

  __syncthreads();   // b2s ready (only barrier)

#pragma unroll
  for (int t2 = 0; t2 < 2; ++t2) {
    int row0 = blockIdx.x * 128 + t2 * 64 + wave * 16;
    int arow = row0 + rlo;

    floatx4 acc[8];
#pragma unroll
    for (int ct = 0; ct < 8; ++ct) { acc[ct][0]=0.f; acc[ct][1]=0.f; acc[ct][2]=0.f; acc[ct][3]=0.f; }
    const int NS = K1 >> 5;
#pragma unroll
    for (int s = 0; s < NS; ++s) {
      shortx8 a = {0,0,0,0,0,0,0,0};
      if (arow < N) a = *(const shortx8*)(in + (size_t)arow * K1 + s * 32 + quad * 8);
      const unsigned short* wp = w1z + ((size_t)(s * 8) * 64 + lane) * 8;
#pragma unroll
      for (int ct = 0; ct < 8; ++ct) {
        shortx8 b = *(const shortx8*)(wp + ct * 512);
        acc[ct] = __builtin_amdgcn_mfma_f32_16x16x32_bf16(a, b, acc[ct], 0, 0, 0);
      }
    }
#pragma unroll
    for (int ct = 0; ct < 8; ++ct) {
#pragma unroll
      for (int r = 0; r < 4; ++r) {
        float v = elu_fast(acc[ct][r] + bm1[ct]);
        tls[wave][quad * 4 + r][ct * 16 + rlo] = f2bf(v);
      }
    }
    // no barrier: tls[wave] is wave-private; DS ops are wave-ordered.

    floatx4 acc2[8];
#pragma unroll
    for (int ct = 0; ct < 8; ++ct) { acc2[ct][0]=0.f; acc2[ct][1]=0.f; acc2[ct][2]=0.f; acc2[ct][3]=0.f; }
#pragma unroll
    for (int s = 0; s < 4; ++s) {
      shortx8 a = *(const shortx8*)&tls[wave][rlo][s * 32 + quad * 8];
      const unsigned short* wp = &b2s[((s * 8) * 64 + lane) * 8];
#pragma unroll
      for (int ct = 0; ct < 8; ++ct) {
        shortx8 b = *(const shortx8*)(wp + ct * 512);
        acc2[ct] = __builtin_amdgcn_mfma_f32_16x16x32_bf16(a, b, acc2[ct], 0, 0, 0);
      }
    }
#pragma unroll
    for (int ct = 0; ct < 8; ++ct) {
#pragma unroll
      for (int r = 0; r < 4; ++r) {
        float v = elu_fast(acc2[ct][r] + bm2[ct]);
        tls[wave][quad * 4 + r][ct * 16 + rlo] = f2bf(v);
      }
    }
    int srow = lane >> 2;           // 0..15
    int schunk = lane & 3;          // 0..3
    int grow = row0 + srow;
#pragma unroll
    for (int k = 0; k < 4; ++k) {
      int ch = schunk + k * 4;      // 16B chunk (8 cols)
      if (grow < N)
        *(shortx8*)(outb + (size_t)grow * 128 + ch * 8) =
            *(const shortx8*)&tls[wave][srow][ch * 8];
    }
  }
}

// ---- pooling (R7-proven): wave per 32-node chunk, lane = 2 channels.
__global__ __launch_bounds__(256) void k_pool(
    const unsigned short* __restrict__ x2, const int* __restrict__ batch,
    float* __restrict__ hgf) {
  int gt = blockIdx.x * 256 + threadIdx.x;
  int chunk = gt >> 6, lane = gt & 63;
  int n0 = chunk * 32;
  if (n0 >= NN) return;
  int nend = n0 + 32; if (nend > NN) nend = NN;
  float ax = 0.f, ay = 0.f;
  const unsigned short* xp = x2 + lane * 2;
  int gcur = batch[n0];
  for (int n = n0; n < nend; ++n) {
    int g = batch[n];
    if (g != gcur) {
      atomicAdd(&hgf[gcur * 128 + lane * 2], ax);
      atomicAdd(&hgf[gcur * 128 + lane * 2 + 1], ay);
      ax = 0.f; ay = 0.f; gcur = g;
    }
    unsigned int v = *(const unsigned int*)(xp + (size_t)n * 128);
    ax += bf2f((unsigned short)(v & 0xFFFF));
    ay += bf2f((unsigned short)(v >> 16));
  }
  atomicAdd(&hgf[gcur * 128 + lane * 2], ax);
  atomicAdd(&hgf[gcur * 128 + lane * 2 + 1], ay);
}

// ---- head MLP: A rows fp32 (pooled), out fp32 = (relu(in@l1+b))@l2+b
__global__ void k_head(const float* __restrict__ in,
                       const unsigned short* __restrict__ w1z, const float* __restrict__ b1,
                       const unsigned short* __restrict__ w2z, const float* __restrict__ b2,
                       float* __restrict__ outf, int N) {
  __shared__ unsigned short tls[4][16][136];
  int lane = threadIdx.x & 63;
  int wave = threadIdx.x >> 6;
  int row0 = blockIdx.x * 64 + wave * 16;
  int rlo = lane & 15, quad = lane >> 4;
  int arow = row0 + rlo;
  floatx4 acc[8];
#pragma unroll
  for (int ct = 0; ct < 8; ++ct) { acc[ct][0]=0.f; acc[ct][1]=0.f; acc[ct][2]=0.f; acc[ct][3]=0.f; }
#pragma unroll
  for (int s = 0; s < 4; ++s) {
    shortx8 a = {0,0,0,0,0,0,0,0};
    if (arow < N) {
      const float* rp = in + (size_t)arow * 128 + s * 32 + quad * 8;
      float4 f0 = *(const float4*)rp;
      float4 f1 = *(const float4*)(rp + 4);
      a[0] = (short)f2bf(f0.x); a[1] = (short)f2bf(f0.y);
      a[2] = (short)f2bf(f0.z); a[3] = (short)f2bf(f0.w);
      a[4] = (short)f2bf(f1.x); a[5] = (short)f2bf(f1.y);
      a[6] = (short)f2bf(f1.z); a[7] = (short)f2bf(f1.w);
    }
    const unsigned short* wp = w1z + ((size_t)(s * 8) * 64 + lane) * 8;
#pragma unroll
    for (int ct = 0; ct < 8; ++ct) {
      shortx8 b = *(const shortx8*)(wp + ct * 512);
      acc[ct] = __builtin_amdgcn_mfma_f32_16x16x32_bf16(a, b, acc[ct], 0, 0, 0);
    }
  }
#pragma unroll
  for (int ct = 0; ct < 8; ++ct) {
    float bm = b1[ct * 16 + rlo];
#pragma unroll
    for (int r = 0; r < 4; ++r) {
      float v = acc[ct][r] + bm;
      v = v > 0.f ? v : 0.f;  // relu
      tls[wave][quad * 4 + r][ct * 16 + rlo] = f2bf(v);
    }
  }
  __syncthreads();
  floatx4 acc2[8];
#pragma unroll
  for (int ct = 0; ct < 8; ++ct) { acc2[ct][0]=0.f; acc2[ct][1]=0.f; acc2[ct][2]=0.f; acc2[ct][3]=0.f; }
#pragma unroll
  for (int s = 0; s < 4; ++s) {
    shortx8 a = *(const shortx8*)&tls[wave][rlo][s * 32 + quad * 8];
    const unsigned short* wp = w2z + ((size_t)(s * 8) * 64 + lane) * 8;
#pragma unroll
    for (int ct = 0; ct < 8; ++ct) {
      shortx8 b = *(const shortx8*)(wp + ct * 512);
      acc2[ct] = __builtin_amdgcn_mfma_f32_16x16x32_bf16(a, b, acc2[ct], 0, 0, 0);
    }
  }
#pragma unroll
  for (int ct = 0; ct < 8; ++ct) {
    float bm = b2[ct * 16 + rlo];
#pragma unroll
    for (int r = 0; r < 4; ++r) {
      int rr = row0 + quad * 4 + r;
      if (rr < N) outf[(size_t)rr * 128 + ct * 16 + rlo] = acc2[ct][r] + bm;
    }
  }
}

extern "C" void kernel_launch(void* const* d_in, const int* in_sizes, int n_in,
                              void* d_out, int out_size, void* d_ws, size_t ws_size,
                              hipStream_t stream) {
  const int* x_idx  = (const int*)d_in[0];
  const int* e_src  = (const int*)d_in[1];
  const int* e_dst  = e_src + NE;
  const int* e_attr = (const int*)d_in[2];
  const int* batch  = (const int*)d_in[3];
  const float* atom = (const float*)d_in[4];
  const float* bond = (const float*)d_in[5];
  const float* we0  = (const float*)d_in[6];
  const float* be0  = (const float*)d_in[7];
  const float* w1_0 = (const float*)d_in[8];
  const float* b1_0 = (const float*)d_in[9];
  const float* w2_0 = (const float*)d_in[10];
  const float* b2_0 = (const float*)d_in[11];
  const float* we1  = (const float*)d_in[12];
  const float* be1  = (const float*)d_in[13];
  const float* w1_1 = (const float*)d_in[14];
  const float* b1_1 = (const float*)d_in[15];
  const float* w2_1 = (const float*)d_in[16];
  const float* b2_1 = (const float*)d_in[17];
  const float* l1w  = (const float*)d_in[18];
  const float* l1b  = (const float*)d_in[19];
  const float* l2w  = (const float*)d_in[20];
  const float* l2b  = (const float*)d_in[21];

  char* ws = (char*)d_ws;
  size_t off = 0;
  auto alloc = [&](size_t bytes) -> void* {
    void* p = ws + off;
    off = (off + bytes + 255) & ~(size_t)255;
    return p;
  };
  int* bcursor = (int*)alloc((size_t)NB * 4);
  int* offs    = (int*)alloc((size_t)NN * 4);
  int* cnts    = (int*)alloc((size_t)NN * 4);
  float* et1   = (float*)alloc(16 * 128 * 4);
  unsigned short* M0 = (unsigned short*)alloc((size_t)1904 * 64 * 2);  // bf16
  float* hgf   = (float*)alloc((size_t)NG * 128 * 4);
  unsigned short* w1_0z = (unsigned short*)alloc(64 * 128 * 2);
  unsigned short* w2_0z = (unsigned short*)alloc(128 * 128 * 2);
  unsigned short* w1_1z = (unsigned short*)alloc(128 * 128 * 2);
  unsigned short* w2_1z = (unsigned short*)alloc(128 * 128 * 2);
  unsigned short* l1z   = (unsigned short*)alloc(128 * 128 * 2);
  unsigned short* l2z   = (unsigned short*)alloc(128 * 128 * 2);
  uint2* pairs = (uint2*)alloc((size_t)NB * PS * 8);       // dead after k_fine
  unsigned int* csr0 = (unsigned int*)alloc((size_t)NB * CS * 4);
  unsigned int* csr1 = (unsigned int*)alloc((size_t)NB * CS * 4);
  unsigned short* x1 = (unsigned short*)alloc((size_t)NN * 128 * 2);
  unsigned short* h1 = (unsigned short*)alloc((size_t)NN * 128 * 2);
  unsigned short* h0 = (unsigned short*)pairs;  // 12.8 MB alias: pairs dead before agg0
  unsigned short* x2 = h1;  // in-place mlp1 (wave reads own rows before writing)

  k_prep<<<885, 256, 0, stream>>>(bond, we0, be0, we1, be1, atom, et1, M0, hgf, bcursor,
                                  w1_0, w2_0, w1_1, w2_1, l1w, l2w,
                                  w1_0z, w2_0z, w1_1z, w2_1z, l1z, l2z);
  k_bin<<<(NE + 4095) / 4096, 256, 0, stream>>>(e_src, e_dst, e_attr, x_idx, bcursor, pairs);
  k_fine<<<NB, 256, 0, stream>>>(pairs, bcursor, offs, cnts, csr0, csr1);
  k_agg0<<<NN / 4, 256, 0, stream>>>(x_idx, atom, M0, offs, cnts, csr0, h0);
  k_mlp_t<64><<<(NN + 127) / 128, 256, 0, stream>>>(h0, w1_0z, b1_0, w2_0z, b2_0, x1, NN);
  k_agg1<<<NN / 4, 256, 0, stream>>>(x1, et1, offs, cnts, csr1, h1);
  k_mlp_t<128><<<(NN + 127) / 128, 256, 0, stream>>>(h1, w1_1z, b1_1, w2_1z, b2_1, x2, NN);
  k_pool<<<(((NN + 31) / 32) * 64 + 255) / 256, 256, 0, stream>>>(x2, batch, hgf);
  k_head<<<(NG + 63) / 64, 256, 0, stream>>>(hgf, l1z, l1b, l2z, l2b, (float*)d_out, NG);
}

// Round 2
// 330.856 us; speedup vs baseline: 1.0114x; 1.0114x over previous
//
#include <hip/hip_runtime.h>
#include <hip/hip_bf16.h>

// GINE on MI355X — fp32 inputs/outputs; bf16 MFMA internals.
static const int NN = 100000;   // nodes
static const int NE = 1600000;  // edges
static const int NG = 512;      // graphs
static const int NB = 391;      // coarse buckets of 256 nodes (dst >> 8)
static const int PS = 4608;     // pairs region per bucket (mean 4096 + 8 sigma)
static const int CS = 4624;     // csr region per bucket (PS + 16 zero-fill slack)

typedef __attribute__((ext_vector_type(8))) short shortx8;
typedef __attribute__((ext_vector_type(4))) float floatx4;
typedef __attribute__((ext_vector_type(2))) float floatx2;

__device__ __forceinline__ float bf2f(unsigned short u) {
  union { unsigned int i; float f; } v; v.i = ((unsigned int)u) << 16; return v.f;
}
__device__ __forceinline__ unsigned short f2bf(float f) {
  union { float f; unsigned int i; } v; v.f = f;
  return (unsigned short)((v.i + 0x7FFFu + ((v.i >> 16) & 1u)) >> 16);
}
__device__ __forceinline__ float elu_fast(float v) {
  return v > 0.f ? v : (__builtin_amdgcn_exp2f(v * 1.44269504f) - 1.f);
}
// unpack packed 2x bf16 -> float2 (2 VALU: shl, and)
__device__ __forceinline__ floatx2 unpk(unsigned int v) {
  union { unsigned int i; float f; } a, b;
  a.i = v << 16; b.i = v & 0xFFFF0000u;
  floatx2 r; r.x = a.f; r.y = b.f; return r;
}

// ---- one prep kernel ----------------------------------------------------
// blocks 0..7: et1 | 8..483: M0 (bf16) | 484..867: weight swizzle |
// 868..883: zero hgf | 884: bcursor init.
__global__ void k_prep(const float* __restrict__ bond,
                       const float* __restrict__ we0, const float* __restrict__ be0,
                       const float* __restrict__ we1, const float* __restrict__ be1,
                       const float* __restrict__ atom,
                       float* __restrict__ et1, unsigned short* __restrict__ M0,
                       float* __restrict__ hgf, int* __restrict__ bcursor,
                       const float* __restrict__ s0, const float* __restrict__ s1,
                       const float* __restrict__ s2, const float* __restrict__ s3,
                       const float* __restrict__ s4, const float* __restrict__ s5,
                       unsigned short* __restrict__ d0, unsigned short* __restrict__ d1,
                       unsigned short* __restrict__ d2, unsigned short* __restrict__ d3,
                       unsigned short* __restrict__ d4, unsigned short* __restrict__ d5) {
  int blk = blockIdx.x, t = threadIdx.x;
  if (blk < 8) {                      // et1[16][128] = bond@we1 + be1
    int i = blk * 256 + t;
    int b = i >> 7, c = i & 127;
    float acc = be1[c];
    for (int k = 0; k < 64; ++k) acc += bond[b * 64 + k] * we1[k * 128 + c];
    et1[i] = acc;
  } else if (blk < 484) {             // M0 (bf16) = relu(atom + bond@we0 + be0)
    int i = (blk - 8) * 256 + t;      // 476*256 == 119*16*64
    int c = i & 63, b = (i >> 6) & 15, a = i >> 10;
    float acc = be0[c];
    for (int k = 0; k < 64; ++k) acc += bond[b * 64 + k] * we0[k * 64 + c];
    acc += atom[a * 64 + c];
    M0[i] = f2bf(acc > 0.f ? acc : 0.f);
  } else if (blk < 868) {             // weight swizzle into MFMA B-frag order
    int task = (blk - 484) >> 6;
    int i = ((blk - 484) & 63) * 256 + t;
    const float* w; unsigned short* wz; int K;
    switch (task) {
      case 0: w = s0; wz = d0; K = 64; break;
      case 1: w = s1; wz = d1; K = 128; break;
      case 2: w = s2; wz = d2; K = 128; break;
      case 3: w = s3; wz = d3; K = 128; break;
      case 4: w = s4; wz = d4; K = 128; break;
      default: w = s5; wz = d5; K = 128; break;
    }
    if (i >= K * 128) return;
    int j = i & 7, lane = (i >> 3) & 63, ct = (i >> 9) & 7, s = i >> 12;
    int k = s * 32 + (lane >> 4) * 8 + j;
    int m = ct * 16 + (lane & 15);
    wz[i] = f2bf(w[k * 128 + m]);
  } else if (blk < 884) {             // zero hgf (512*128 floats)
    int base = (blk - 868) * 4096;
#pragma unroll
    for (int k = 0; k < 16; ++k) hgf[base + k * 256 + t] = 0.f;
  } else {                            // bcursor fixed bases
    if (t < NB) bcursor[t] = t * PS;
    int u = t + 256;
    if (u < NB) bcursor[u] = u * PS;
  }
}

// Pass B: bin 4096-edge chunks by coarse bucket into fixed per-bucket regions.
__global__ void k_bin(const int* __restrict__ src, const int* __restrict__ dstp,
                      const int* __restrict__ ea, const int* __restrict__ x_idx,
                      int* __restrict__ bcursor, uint2* __restrict__ pairs) {
  __shared__ int cnt[512];
  __shared__ int incl[512];
  __shared__ int cur[NB];
  __shared__ int rbase[NB];
  __shared__ uint2 stage[4096];
  int t = threadIdx.x;
  int e0 = blockIdx.x * 4096;
  int ecnt = NE - e0; if (ecnt > 4096) ecnt = 4096;
  cnt[t] = 0; cnt[t + 256] = 0;
  __syncthreads();
  for (int k = 0; k < 16; ++k) {
    int i = k * 256 + t;
    if (i < ecnt) atomicAdd(&cnt[dstp[e0 + i] >> 8], 1);
  }
  __syncthreads();
  incl[t] = cnt[t]; incl[t + 256] = cnt[t + 256];
  __syncthreads();
  for (int d = 1; d < 512; d <<= 1) {
    int v0 = (t >= d) ? incl[t - d] : 0;
    int v1 = (t + 256 >= d) ? incl[t + 256 - d] : 0;
    __syncthreads();
    incl[t] += v0; incl[t + 256] += v1;
    __syncthreads();
  }
  if (t < NB) { cur[t] = incl[t] - cnt[t]; if (cnt[t]) rbase[t] = atomicAdd(&bcursor[t], cnt[t]); }
  int u = t + 256;
  if (u < NB) { cur[u] = incl[u] - cnt[u]; if (cnt[u]) rbase[u] = atomicAdd(&bcursor[u], cnt[u]); }
  __syncthreads();
  for (int k = 0; k < 16; ++k) {
    int i = k * 256 + t;
    if (i < ecnt) {
      int e = e0 + i;
      int d = dstp[e];
      int s = src[e];
      unsigned int pk = (unsigned int)s | ((unsigned int)(x_idx[s] * 16 + ea[e]) << 17);
      int p = atomicAdd(&cur[d >> 8], 1);
      stage[p] = make_uint2((unsigned int)d, pk);
    }
  }
  __syncthreads();
  for (int j = t; j < ecnt; j += 256) {   // bucket from dst — no search
    uint2 p = stage[j];
    int b = (int)(p.x >> 8);
    int excl = incl[b] - cnt[b];
    pairs[rbase[b] + (j - excl)] = p;
  }
}

// Pass C: fine counting-sort per bucket; absolute offs + cnts; 16 zero slots.
//   csr0[i] = M0-row byte offset (bf16 rows: idx17*128)
//   csr1[i] = (src*256) | bond
__global__ void k_fine(const uint2* __restrict__ pairs, const int* __restrict__ bcursor,
                       int* __restrict__ offs, int* __restrict__ cnts,
                       unsigned int* __restrict__ csr0, unsigned int* __restrict__ csr1) {
  __shared__ int cnt[256];
  __shared__ int incl[256];
  __shared__ int cur[256];
  int b = blockIdx.x;
  int t = threadIdx.x;
  int start = b * PS;
  int endv = bcursor[b];
  int cbase = b * CS;
  int base_n = b << 8;
  cnt[t] = 0;
  __syncthreads();
  for (int j = start + t; j < endv; j += 256)
    atomicAdd(&cnt[(int)pairs[j].x - base_n], 1);
  __syncthreads();
  incl[t] = cnt[t];
  __syncthreads();
  for (int d = 1; d < 256; d <<= 1) {
    int v = (t >= d) ? incl[t - d] : 0;
    __syncthreads();
    incl[t] += v;
    __syncthreads();
  }
  int excl = incl[t] - cnt[t];
  cur[t] = excl;
  int node = base_n + t;
  if (node < NN) { offs[node] = cbase + excl; cnts[node] = cnt[t]; }
  __syncthreads();
  for (int j = start + t; j < endv; j += 256) {
    uint2 p = pairs[j];
    int pos = cbase + atomicAdd(&cur[(int)p.x - base_n], 1);
    unsigned int pk = p.y;
    unsigned int idx17 = pk >> 17;
    csr0[pos] = idx17 << 7;                 // bf16 M0 rows: 128 B
    csr1[pos] = ((pk & 0x1FFFFu) << 8) | (idx17 & 15u);
  }
  __syncthreads();
  int total = incl[255];
  if (t < 16) { csr0[cbase + total + t] = 0u; csr1[cbase + total + t] = 0u; }
}

// ---- aggregation layer 0 (round-0 proven): wave per node; bf16 M0, two
// edges per gather instruction; packed-f32 accumulate; shfl_xor(32) merge.
__global__ __launch_bounds__(256) void k_agg0(
    const int* __restrict__ x_idx, const float* __restrict__ atom,
    const unsigned short* __restrict__ M0, const int* __restrict__ offs,
    const int* __restrict__ cnts,
    const unsigned int* __restrict__ csr0, unsigned short* __restrict__ h0) {
  int t = threadIdx.x, lane = t & 63;
  int half = lane >> 5, c = lane & 31;
  int n = __builtin_amdgcn_readfirstlane(blockIdx.x * 4 + (t >> 6));
  if (n >= NN) return;
  int s = offs[n], e = s + cnts[n];
  const char* Mb = (const char*)M0;
  unsigned int voff = (unsigned int)c * 4u;
  floatx2 acc; acc.x = 0.f; acc.y = 0.f;
  if (half == 0) {   // self term: h = x + agg
    float2 sv = *(const float2*)((const char*)atom +
                                 ((size_t)(unsigned)x_idx[n] << 8) + (size_t)c * 8u);
    acc.x = sv.x; acc.y = sv.y;
  }
  for (int i = s; i < e; i += 16) {
    unsigned int a0 = csr0[i + 0],  b0 = csr0[i + 1];
    unsigned int a1 = csr0[i + 2],  b1 = csr0[i + 3];
    unsigned int a2 = csr0[i + 4],  b2 = csr0[i + 5];
    unsigned int a3 = csr0[i + 6],  b3 = csr0[i + 7];
    unsigned int a4 = csr0[i + 8],  b4 = csr0[i + 9];
    unsigned int a5 = csr0[i + 10], b5 = csr0[i + 11];
    unsigned int a6 = csr0[i + 12], b6 = csr0[i + 13];
    unsigned int a7 = csr0[i + 14], b7 = csr0[i + 15];
    unsigned int q0 = half ? b0 : a0, q1 = half ? b1 : a1;
    unsigned int q2 = half ? b2 : a2, q3 = half ? b3 : a3;
    unsigned int q4 = half ? b4 : a4, q5 = half ? b5 : a5;
    unsigned int q6 = half ? b6 : a6, q7 = half ? b7 : a7;
    floatx2 m0, m1, m2, m3, m4, m5, m6, m7;
    m0.x = m0.y = (i + 0 + half < e) ? 1.f : 0.f;
    m1.x = m1.y = (i + 2 + half < e) ? 1.f : 0.f;
    m2.x = m2.y = (i + 4 + half < e) ? 1.f : 0.f;
    m3.x = m3.y = (i + 6 + half < e) ? 1.f : 0.f;
    m4.x = m4.y = (i + 8 + half < e) ? 1.f : 0.f;
    m5.x = m5.y = (i + 10 + half < e) ? 1.f : 0.f;
    m6.x = m6.y = (i + 12 + half < e) ? 1.f : 0.f;
    m7.x = m7.y = (i + 14 + half < e) ? 1.f : 0.f;
    unsigned int v0 = *(const unsigned int*)(Mb + q0 + voff);
    unsigned int v1 = *(const unsigned int*)(Mb + q1 + voff);
    unsigned int v2 = *(const unsigned int*)(Mb + q2 + voff);
    unsigned int v3 = *(const unsigned int*)(Mb + q3 + voff);
    unsigned int v4 = *(const unsigned int*)(Mb + q4 + voff);
    unsigned int v5 = *(const unsigned int*)(Mb + q5 + voff);
    unsigned int v6 = *(const unsigned int*)(Mb + q6 + voff);
    unsigned int v7 = *(const unsigned int*)(Mb + q7 + voff);
    acc = __builtin_elementwise_fma(m0, unpk(v0), acc);
    acc = __builtin_elementwise_fma(m1, unpk(v1), acc);
    acc = __builtin_elementwise_fma(m2, unpk(v2), acc);
    acc = __builtin_elementwise_fma(m3, unpk(v3), acc);
    acc = __builtin_elementwise_fma(m4, unpk(v4), acc);
    acc = __builtin_elementwise_fma(m5, unpk(v5), acc);
    acc = __builtin_elementwise_fma(m6, unpk(v6), acc);
    acc = __builtin_elementwise_fma(m7, unpk(v7), acc);
  }
  float ax = acc.x + __shfl_xor(acc.x, 32);
  float ay = acc.y + __shfl_xor(acc.y, 32);
  if (half == 0) {
    unsigned int o = (unsigned int)f2bf(ax) | ((unsigned int)f2bf(ay) << 16);
    *(unsigned int*)(h0 + (size_t)n * 64 + c * 2) = o;
  }
}

// ---- aggregation layer 1 edge update: half-wave per edge.
// 32 lanes x dwordx2 = one 256 B x1 row (2 edges/gather-instruction);
// lane owns 4 channels; et slice via ONE ds_read_b128 from a contiguous
// 512 B row block (standard conflict-free pattern; row stride bank-aligned).
__device__ __forceinline__ void upd1h(unsigned int q, float m,
    const char* xb, const char* etb, unsigned int claneoff,
    floatx2& a0, floatx2& a1) {
  floatx2 mm; mm.x = m; mm.y = m;
  floatx2 z2; z2.x = 0.f; z2.y = 0.f;
  uint2 v = *(const uint2*)(xb + (size_t)((q & 0xFFFFFF00u) | claneoff));
  floatx4 ef = *(const floatx4*)(etb + ((q & 15u) << 9));   // row*512B + c*16B
  floatx2 e0; e0.x = ef.x; e0.y = ef.y;
  floatx2 e1; e1.x = ef.z; e1.y = ef.w;
  a0 = __builtin_elementwise_fma(mm, __builtin_elementwise_max(unpk(v.x) + e0, z2), a0);
  a1 = __builtin_elementwise_fma(mm, __builtin_elementwise_max(unpk(v.y) + e1, z2), a1);
}

// ---- aggregation layer 1: wave per node; HALF-wave per edge.
__global__ __launch_bounds__(256) void k_agg1(
    const unsigned short* __restrict__ x1, const float* __restrict__ et1,
    const int* __restrict__ offs, const int* __restrict__ cnts,
    const unsigned int* __restrict__ csr1, unsigned short* __restrict__ h1) {
  __shared__ float etl[16 * 128];          // plain 16 rows x 128 ch, 8 KB
  int t = threadIdx.x;
#pragma unroll
  for (int k = 0; k < 8; ++k) etl[k * 256 + t] = et1[k * 256 + t];
  __syncthreads();
  int lane = t & 63;
  int half = lane >> 5, c = lane & 31;     // edge slot / channel-quad lane
  int n = __builtin_amdgcn_readfirstlane(blockIdx.x * 4 + (t >> 6));
  if (n >= NN) return;
  int s = offs[n], e = s + cnts[n];
  const char* xb = (const char*)x1;
  const char* etb = (const char*)etl + (size_t)(c * 16);    // 16 B slice per lane
  unsigned int claneoff = (unsigned int)(c * 8);   // bits [7:3], row offs bits >=8
  floatx2 a0, a1;                          // channels 4c..4c+1, 4c+2..4c+3
  a0.x = a0.y = a1.x = a1.y = 0.f;
  if (half == 0) {                         // self term: h = x + agg
    uint2 v = *(const uint2*)(xb + ((size_t)(unsigned)n << 8) + claneoff);
    a0 = unpk(v.x); a1 = unpk(v.y);
  }
  const unsigned int* cp = csr1 + s + half;
  for (int r = e - s; r > 0; r -= 8, cp += 8) {
    unsigned int q0 = cp[0];               // edge i + 0 + half
    unsigned int q1 = cp[2];               // edge i + 2 + half
    unsigned int q2 = cp[4];               // edge i + 4 + half
    unsigned int q3 = cp[6];               // edge i + 6 + half
    float m0 = (half < r) ? 1.f : 0.f;
    float m1 = (half + 2 < r) ? 1.f : 0.f;
    float m2 = (half + 4 < r) ? 1.f : 0.f;
    float m3 = (half + 6 < r) ? 1.f : 0.f;
    upd1h(q0, m0, xb, etb, claneoff, a0, a1);
    upd1h(q1, m1, xb, etb, claneoff, a0, a1);
    upd1h(q2, m2, xb, etb, claneoff, a0, a1);
    upd1h(q3, m3, xb, etb, claneoff, a0, a1);
  }
  // merge the two halves (lane bit 5)
  a0.x += __shfl_xor(a0.x, 32); a0.y += __shfl_xor(a0.y, 32);
  a1.x += __shfl_xor(a1.x, 32); a1.y += __shfl_xor(a1.y, 32);
  if (half == 0) {
    uint2 o;
    o.x = (unsigned int)f2bf(a0.x) | ((unsigned int)f2bf(a0.y) << 16);
    o.y = (unsigned int)f2bf(a1.x) | ((unsigned int)f2bf(a1.y) << 16);
    *(uint2*)((char*)h1 + ((size_t)n << 8) + claneoff) = o;
  }
}

// ---- double-GEMM MLP: 128 rows/block (2 tiles), w2 in LDS, one barrier,
// wave-private tls, coalesced dwordx4 stores.
template <int K1>
__global__ __launch_bounds__(256) void k_mlp_t(
    const unsigned short* __restrict__ in,
    const unsigned short* __restrict__ w1z, const float* __restrict__ b1,
    const unsigned short* __restrict__ w2z, const float* __restrict__ b2,
    unsigned short* __restrict__ outb, int N) {
  __shared__ unsigned short tls[4][16][136];   // wave-private mid/out tile
  __shared__ unsigned short b2s[16384];        // 32 KB staged w2 frags
  int t = threadIdx.x;
  int lane = t & 63;
  int wave = t >> 6;
  int rlo = lane & 15, quad = lane >> 4;

#pragma unroll
  for (int k = 0; k < 8; ++k)
    *(shortx8*)&b2s[(k * 256 + t) * 8] = *(const shortx8*)&w2z[(k * 256 + t) * 8];

  float bm1[8], bm2[8];
#pragma unroll
  for (int ct = 0; ct < 8; ++ct) { bm1[ct] = b1[ct * 16 + rlo]; bm2[ct] = b2[ct * 16 + rlo]; }

  __syncthreads();   // b2s ready (only barrier)

#pragma unroll
  for (int t2 = 0; t2 < 2; ++t2) {
    int row0 = blockIdx.x * 128 + t2 * 64 + wave * 16;
    int arow = row0 + rlo;

    floatx4 acc[8];
#pragma unroll
    for (int ct = 0; ct < 8; ++ct) { acc[ct][0]=0.f; acc[ct][1]=0.f; acc[ct][2]=0.f; acc[ct][3]=0.f; }
    const int NS = K1 >> 5;
#pragma unroll
    for (int s = 0; s < NS; ++s) {
      shortx8 a = {0,0,0,0,0,0,0,0};
      if (arow < N) a = *(const shortx8*)(in + (size_t)arow * K1 + s * 32 + quad * 8);
      const unsigned short* wp = w1z + ((size_t)(s * 8) * 64 + lane) * 8;
#pragma unroll
      for (int ct = 0; ct < 8; ++ct) {
        shortx8 b = *(const shortx8*)(wp + ct * 512);
        acc[ct] = __builtin_amdgcn_mfma_f32_16x16x32_bf16(a, b, acc[ct], 0, 0, 0);
      }
    }
#pragma unroll
    for (int ct = 0; ct < 8; ++ct) {
#pragma unroll
      for (int r = 0; r < 4; ++r) {
        float v = elu_fast(acc[ct][r] + bm1[ct]);
        tls[wave][quad * 4 + r][ct * 16 + rlo] = f2bf(v);
      }
    }
    // no barrier: tls[wave] is wave-private; DS ops are wave-ordered.

    floatx4 acc2[8];
#pragma unroll
    for (int ct = 0; ct < 8; ++ct) { acc2[ct][0]=0.f; acc2[ct][1]=0.f; acc2[ct][2]=0.f; acc2[ct][3]=0.f; }
#pragma unroll
    for (int s = 0; s < 4; ++s) {
      shortx8 a = *(const shortx8*)&tls[wave][rlo][s * 32 + quad * 8];
      const unsigned short* wp = &b2s[((s * 8) * 64 + lane) * 8];
#pragma unroll
      for (int ct = 0; ct < 8; ++ct) {
        shortx8 b = *(const shortx8*)(wp + ct * 512);
        acc2[ct] = __builtin_amdgcn_mfma_f32_16x16x32_bf16(a, b, acc2[ct], 0, 0, 0);
      }
    }
#pragma unroll
    for (int ct = 0; ct < 8; ++ct) {
#pragma unroll
      for (int r = 0; r < 4; ++r) {
        float v = elu_fast(acc2[ct][r] + bm2[ct]);
        tls[wave][quad * 4 + r][ct * 16 + rlo] = f2bf(v);
      }
    }
    int srow = lane >> 2;           // 0..15
    int schunk = lane & 3;          // 0..3
    int grow = row0 + srow;
#pragma unroll
    for (int k = 0; k < 4; ++k) {
      int ch = schunk + k * 4;      // 16B chunk (8 cols)
      if (grow < N)
        *(shortx8*)(outb + (size_t)grow * 128 + ch * 8) =
            *(const shortx8*)&tls[wave][srow][ch * 8];
    }
  }
}

// ---- pooling (R7-proven): wave per 32-node chunk, lane = 2 channels.
__global__ __launch_bounds__(256) void k_pool(
    const unsigned short* __restrict__ x2, const int* __restrict__ batch,
    float* __restrict__ hgf) {
  int gt = blockIdx.x * 256 + threadIdx.x;
  int chunk = gt >> 6, lane = gt & 63;
  int n0 = chunk * 32;
  if (n0 >= NN) return;
  int nend = n0 + 32; if (nend > NN) nend = NN;
  float ax = 0.f, ay = 0.f;
  const unsigned short* xp = x2 + lane * 2;
  int gcur = batch[n0];
  for (int n = n0; n < nend; ++n) {
    int g = batch[n];
    if (g != gcur) {
      atomicAdd(&hgf[gcur * 128 + lane * 2], ax);
      atomicAdd(&hgf[gcur * 128 + lane * 2 + 1], ay);
      ax = 0.f; ay = 0.f; gcur = g;
    }
    unsigned int v = *(const unsigned int*)(xp + (size_t)n * 128);
    ax += bf2f((unsigned short)(v & 0xFFFF));
    ay += bf2f((unsigned short)(v >> 16));
  }
  atomicAdd(&hgf[gcur * 128 + lane * 2], ax);
  atomicAdd(&hgf[gcur * 128 + lane * 2 + 1], ay);
}

// ---- head MLP: A rows fp32 (pooled), out fp32 = (relu(in@l1+b))@l2+b
__global__ void k_head(const float* __restrict__ in,
                       const unsigned short* __restrict__ w1z, const float* __restrict__ b1,
                       const unsigned short* __restrict__ w2z, const float* __restrict__ b2,
                       float* __restrict__ outf, int N) {
  __shared__ unsigned short tls[4][16][136];
  int lane = threadIdx.x & 63;
  int wave = threadIdx.x >> 6;
  int row0 = blockIdx.x * 64 + wave * 16;
  int rlo = lane & 15, quad = lane >> 4;
  int arow = row0 + rlo;
  floatx4 acc[8];
#pragma unroll
  for (int ct = 0; ct < 8; ++ct) { acc[ct][0]=0.f; acc[ct][1]=0.f; acc[ct][2]=0.f; acc[ct][3]=0.f; }
#pragma unroll
  for (int s = 0; s < 4; ++s) {
    shortx8 a = {0,0,0,0,0,0,0,0};
    if (arow < N) {
      const float* rp = in + (size_t)arow * 128 + s * 32 + quad * 8;
      float4 f0 = *(const float4*)rp;
      float4 f1 = *(const float4*)(rp + 4);
      a[0] = (short)f2bf(f0.x); a[1] = (short)f2bf(f0.y);
      a[2] = (short)f2bf(f0.z); a[3] = (short)f2bf(f0.w);
      a[4] = (short)f2bf(f1.x); a[5] = (short)f2bf(f1.y);
      a[6] = (short)f2bf(f1.z); a[7] = (short)f2bf(f1.w);
    }
    const unsigned short* wp = w1z + ((size_t)(s * 8) * 64 + lane) * 8;
#pragma unroll
    for (int ct = 0; ct < 8; ++ct) {
      shortx8 b = *(const shortx8*)(wp + ct * 512);
      acc[ct] = __builtin_amdgcn_mfma_f32_16x16x32_bf16(a, b, acc[ct], 0, 0, 0);
    }
  }
#pragma unroll
  for (int ct = 0; ct < 8; ++ct) {
    float bm = b1[ct * 16 + rlo];
#pragma unroll
    for (int r = 0; r < 4; ++r) {
      float v = acc[ct][r] + bm;
      v = v > 0.f ? v : 0.f;  // relu
      tls[wave][quad * 4 + r][ct * 16 + rlo] = f2bf(v);
    }
  }
  __syncthreads();
  floatx4 acc2[8];
#pragma unroll
  for (int ct = 0; ct < 8; ++ct) { acc2[ct][0]=0.f; acc2[ct][1]=0.f; acc2[ct][2]=0.f; acc2[ct][3]=0.f; }
#pragma unroll
  for (int s = 0; s < 4; ++s) {
    shortx8 a = *(const shortx8*)&tls[wave][rlo][s * 32 + quad * 8];
    const unsigned short* wp = w2z + ((size_t)(s * 8) * 64 + lane) * 8;
#pragma unroll
    for (int ct = 0; ct < 8; ++ct) {
      shortx8 b = *(const shortx8*)(wp + ct * 512);
      acc2[ct] = __builtin_amdgcn_mfma_f32_16x16x32_bf16(a, b, acc2[ct], 0, 0, 0);
    }
  }
#pragma unroll
  for (int ct = 0; ct < 8; ++ct) {
    float bm = b2[ct * 16 + rlo];
#pragma unroll
    for (int r = 0; r < 4; ++r) {
      int rr = row0 + quad * 4 + r;
      if (rr < N) outf[(size_t)rr * 128 + ct * 16 + rlo] = acc2[ct][r] + bm;
    }
  }
}

extern "C" void kernel_launch(void* const* d_in, const int* in_sizes, int n_in,
                              void* d_out, int out_size, void* d_ws, size_t ws_size,
                              hipStream_t stream) {
  const int* x_idx  = (const int*)d_in[0];
  const int* e_src  = (const int*)d_in[1];
  const int* e_dst  = e_src + NE;
  const int* e_attr = (const int*)d_in[2];
  const int* batch  = (const int*)d_in[3];
  const float* atom = (const float*)d_in[4];
  const float* bond = (const float*)d_in[5];
  const float* we0  = (const float*)d_in[6];
  const float* be0  = (const float*)d_in[7];
  const float* w1_0 = (const float*)d_in[8];
  const float* b1_0 = (const float*)d_in[9];
  const float* w2_0 = (const float*)d_in[10];
  const float* b2_0 = (const float*)d_in[11];
  const float* we1  = (const float*)d_in[12];
  const float* be1  = (const float*)d_in[13];
  const float* w1_1 = (const float*)d_in[14];
  const float* b1_1 = (const float*)d_in[15];
  const float* w2_1 = (const float*)d_in[16];
  const float* b2_1 = (const float*)d_in[17];
  const float* l1w  = (const float*)d_in[18];
  const float* l1b  = (const float*)d_in[19];
  const float* l2w  = (const float*)d_in[20];
  const float* l2b  = (const float*)d_in[21];

  char* ws = (char*)d_ws;
  size_t off = 0;
  auto alloc = [&](size_t bytes) -> void* {
    void* p = ws + off;
    off = (off + bytes + 255) & ~(size_t)255;
    return p;
  };
  int* bcursor = (int*)alloc((size_t)NB * 4);
  int* offs    = (int*)alloc((size_t)NN * 4);
  int* cnts    = (int*)alloc((size_t)NN * 4);
  float* et1   = (float*)alloc(16 * 128 * 4);
  unsigned short* M0 = (unsigned short*)alloc((size_t)1904 * 64 * 2);  // bf16
  float* hgf   = (float*)alloc((size_t)NG * 128 * 4);
  unsigned short* w1_0z = (unsigned short*)alloc(64 * 128 * 2);
  unsigned short* w2_0z = (unsigned short*)alloc(128 * 128 * 2);
  unsigned short* w1_1z = (unsigned short*)alloc(128 * 128 * 2);
  unsigned short* w2_1z = (unsigned short*)alloc(128 * 128 * 2);
  unsigned short* l1z   = (unsigned short*)alloc(128 * 128 * 2);
  unsigned short* l2z   = (unsigned short*)alloc(128 * 128 * 2);
  uint2* pairs = (uint2*)alloc((size_t)NB * PS * 8);       // dead after k_fine
  unsigned int* csr0 = (unsigned int*)alloc((size_t)NB * CS * 4);
  unsigned int* csr1 = (unsigned int*)alloc((size_t)NB * CS * 4);
  unsigned short* x1 = (unsigned short*)alloc((size_t)NN * 128 * 2);
  unsigned short* h1 = (unsigned short*)alloc((size_t)NN * 128 * 2);
  unsigned short* h0 = (unsigned short*)pairs;  // 12.8 MB alias: pairs dead before agg0
  unsigned short* x2 = h1;  // in-place mlp1 (wave reads own rows before writing)

  k_prep<<<885, 256, 0, stream>>>(bond, we0, be0, we1, be1, atom, et1, M0, hgf, bcursor,
                                  w1_0, w2_0, w1_1, w2_1, l1w, l2w,
                                  w1_0z, w2_0z, w1_1z, w2_1z, l1z, l2z);
  k_bin<<<(NE + 4095) / 4096, 256, 0, stream>>>(e_src, e_dst, e_attr, x_idx, bcursor, pairs);
  k_fine<<<NB, 256, 0, stream>>>(pairs, bcursor, offs, cnts, csr0, csr1);
  k_agg0<<<NN / 4, 256, 0, stream>>>(x_idx, atom, M0, offs, cnts, csr0, h0);
  k_mlp_t<64><<<(NN + 127) / 128, 256, 0, stream>>>(h0, w1_0z, b1_0, w2_0z, b2_0, x1, NN);
  k_agg1<<<NN / 4, 256, 0, stream>>>(x1, et1, offs, cnts, csr1, h1);
  k_mlp_t<128><<<(NN + 127) / 128, 256, 0, stream>>>(h1, w1_1z, b1_1, w2_1z, b2_1, x2, NN);
  k_pool<<<(((NN + 31) / 32) * 64 + 255) / 256, 256, 0, stream>>>(x2, batch, hgf);
  k_head<<<(NG + 63) / 64, 256, 0, stream>>>(hgf, l1z, l1b, l2z, l2b, (float*)d_out, NG);
}

// Round 3
// 328.074 us; speedup vs baseline: 1.0200x; 1.0085x over previous
//
#include <hip/hip_runtime.h>
#include <hip/hip_bf16.h>

// GINE on MI355X — fp32 inputs/outputs; bf16 MFMA internals.
static const int NN = 100000;   // nodes
static const int NE = 1600000;  // edges
static const int NG = 512;      // graphs
static const int NB = 391;      // coarse buckets of 256 nodes (dst >> 8)
static const int PS = 4608;     // pairs region per bucket (mean 4096 + 8 sigma)
static const int CS = 6400;     // csr region per bucket (PS + 256*7 pad slack)

typedef __attribute__((ext_vector_type(8))) short shortx8;
typedef __attribute__((ext_vector_type(4))) float floatx4;
typedef __attribute__((ext_vector_type(2))) float floatx2;

__device__ __forceinline__ float bf2f(unsigned short u) {
  union { unsigned int i; float f; } v; v.i = ((unsigned int)u) << 16; return v.f;
}
__device__ __forceinline__ unsigned short f2bf(float f) {
  union { float f; unsigned int i; } v; v.f = f;
  return (unsigned short)((v.i + 0x7FFFu + ((v.i >> 16) & 1u)) >> 16);
}
__device__ __forceinline__ float elu_fast(float v) {
  return v > 0.f ? v : (__builtin_amdgcn_exp2f(v * 1.44269504f) - 1.f);
}
// unpack packed 2x bf16 -> float2 (2 VALU: shl, and)
__device__ __forceinline__ floatx2 unpk(unsigned int v) {
  union { unsigned int i; float f; } a, b;
  a.i = v << 16; b.i = v & 0xFFFF0000u;
  floatx2 r; r.x = a.f; r.y = b.f; return r;
}

// ---- one prep kernel ----------------------------------------------------
// blocks 0..7: et1 | 8..483: M0 (bf16) | 484..867: weight swizzle |
// 868..883: zero hgf | 884: bcursor init + sentinel rows (M0 zero, x1 -inf).
__global__ void k_prep(const float* __restrict__ bond,
                       const float* __restrict__ we0, const float* __restrict__ be0,
                       const float* __restrict__ we1, const float* __restrict__ be1,
                       const float* __restrict__ atom,
                       float* __restrict__ et1, unsigned short* __restrict__ M0,
                       float* __restrict__ hgf, int* __restrict__ bcursor,
                       unsigned short* __restrict__ x1s,
                       const float* __restrict__ s0, const float* __restrict__ s1,
                       const float* __restrict__ s2, const float* __restrict__ s3,
                       const float* __restrict__ s4, const float* __restrict__ s5,
                       unsigned short* __restrict__ d0, unsigned short* __restrict__ d1,
                       unsigned short* __restrict__ d2, unsigned short* __restrict__ d3,
                       unsigned short* __restrict__ d4, unsigned short* __restrict__ d5) {
  int blk = blockIdx.x, t = threadIdx.x;
  if (blk < 8) {                      // et1[16][128] = bond@we1 + be1
    int i = blk * 256 + t;
    int b = i >> 7, c = i & 127;
    float acc = be1[c];
    for (int k = 0; k < 64; ++k) acc += bond[b * 64 + k] * we1[k * 128 + c];
    et1[i] = acc;
  } else if (blk < 484) {             // M0 (bf16) = relu(atom + bond@we0 + be0)
    int i = (blk - 8) * 256 + t;      // 476*256 == 119*16*64
    int c = i & 63, b = (i >> 6) & 15, a = i >> 10;
    float acc = be0[c];
    for (int k = 0; k < 64; ++k) acc += bond[b * 64 + k] * we0[k * 64 + c];
    acc += atom[a * 64 + c];
    M0[i] = f2bf(acc > 0.f ? acc : 0.f);
  } else if (blk < 868) {             // weight swizzle into MFMA B-frag order
    int task = (blk - 484) >> 6;
    int i = ((blk - 484) & 63) * 256 + t;
    const float* w; unsigned short* wz; int K;
    switch (task) {
      case 0: w = s0; wz = d0; K = 64; break;
      case 1: w = s1; wz = d1; K = 128; break;
      case 2: w = s2; wz = d2; K = 128; break;
      case 3: w = s3; wz = d3; K = 128; break;
      case 4: w = s4; wz = d4; K = 128; break;
      default: w = s5; wz = d5; K = 128; break;
    }
    if (i >= K * 128) return;
    int j = i & 7, lane = (i >> 3) & 63, ct = (i >> 9) & 7, s = i >> 12;
    int k = s * 32 + (lane >> 4) * 8 + j;
    int m = ct * 16 + (lane & 15);
    wz[i] = f2bf(w[k * 128 + m]);
  } else if (blk < 884) {             // zero hgf (512*128 floats)
    int base = (blk - 868) * 4096;
#pragma unroll
    for (int k = 0; k < 16; ++k) hgf[base + k * 256 + t] = 0.f;
  } else {                            // bcursor fixed bases + sentinel rows
    if (t < NB) bcursor[t] = t * PS;
    int u = t + 256;
    if (u < NB) bcursor[u] = u * PS;
    if (t < 32) ((unsigned int*)(M0 + 1904 * 64))[t] = 0u;          // zero row
    if (t < 64) ((unsigned int*)(x1s + (size_t)NN * 128))[t] = 0xFF80FF80u; // -inf row
  }
}

// Pass B: bin 4096-edge chunks by coarse bucket into fixed per-bucket regions.
__global__ void k_bin(const int* __restrict__ src, const int* __restrict__ dstp,
                      const int* __restrict__ ea, const int* __restrict__ x_idx,
                      int* __restrict__ bcursor, uint2* __restrict__ pairs) {
  __shared__ int cnt[512];
  __shared__ int incl[512];
  __shared__ int cur[NB];
  __shared__ int rbase[NB];
  __shared__ uint2 stage[4096];
  int t = threadIdx.x;
  int e0 = blockIdx.x * 4096;
  int ecnt = NE - e0; if (ecnt > 4096) ecnt = 4096;
  cnt[t] = 0; cnt[t + 256] = 0;
  __syncthreads();
  for (int k = 0; k < 16; ++k) {
    int i = k * 256 + t;
    if (i < ecnt) atomicAdd(&cnt[dstp[e0 + i] >> 8], 1);
  }
  __syncthreads();
  incl[t] = cnt[t]; incl[t + 256] = cnt[t + 256];
  __syncthreads();
  for (int d = 1; d < 512; d <<= 1) {
    int v0 = (t >= d) ? incl[t - d] : 0;
    int v1 = (t + 256 >= d) ? incl[t + 256 - d] : 0;
    __syncthreads();
    incl[t] += v0; incl[t + 256] += v1;
    __syncthreads();
  }
  if (t < NB) { cur[t] = incl[t] - cnt[t]; if (cnt[t]) rbase[t] = atomicAdd(&bcursor[t], cnt[t]); }
  int u = t + 256;
  if (u < NB) { cur[u] = incl[u] - cnt[u]; if (cnt[u]) rbase[u] = atomicAdd(&bcursor[u], cnt[u]); }
  __syncthreads();
  for (int k = 0; k < 16; ++k) {
    int i = k * 256 + t;
    if (i < ecnt) {
      int e = e0 + i;
      int d = dstp[e];
      int s = src[e];
      unsigned int pk = (unsigned int)s | ((unsigned int)(x_idx[s] * 16 + ea[e]) << 17);
      int p = atomicAdd(&cur[d >> 8], 1);
      stage[p] = make_uint2((unsigned int)d, pk);
    }
  }
  __syncthreads();
  for (int j = t; j < ecnt; j += 256) {   // bucket from dst — no search
    uint2 p = stage[j];
    int b = (int)(p.x >> 8);
    int excl = incl[b] - cnt[b];
    pairs[rbase[b] + (j - excl)] = p;
  }
}

// Pass C: fine counting-sort per bucket; segments padded to multiples of 8
// with sentinel entries (contribution exactly 0 in both agg kernels).
//   csr0[i] = M0-row byte offset (bf16 rows: idx17*128); pad -> zero row 1904
//   csr1[i] = (src*256) | bond; pad -> -inf row NN, bond 0
__global__ void k_fine(const uint2* __restrict__ pairs, const int* __restrict__ bcursor,
                       int* __restrict__ offs, int* __restrict__ cnts,
                       unsigned int* __restrict__ csr0, unsigned int* __restrict__ csr1) {
  __shared__ int cnt[256];
  __shared__ int incl[256];
  __shared__ int cur[256];
  int b = blockIdx.x;
  int t = threadIdx.x;
  int start = b * PS;
  int endv = bcursor[b];
  int cbase = b * CS;
  int base_n = b << 8;
  cnt[t] = 0;
  __syncthreads();
  for (int j = start + t; j < endv; j += 256)
    atomicAdd(&cnt[(int)pairs[j].x - base_n], 1);
  __syncthreads();
  int myc = cnt[t];
  int myp = (myc + 7) & ~7;          // padded count
  incl[t] = myp;
  __syncthreads();
  for (int d = 1; d < 256; d <<= 1) {
    int v = (t >= d) ? incl[t - d] : 0;
    __syncthreads();
    incl[t] += v;
    __syncthreads();
  }
  int excl = incl[t] - myp;          // padded exclusive prefix
  cur[t] = excl;
  int node = base_n + t;
  if (node < NN) { offs[node] = cbase + excl; cnts[node] = myc; }
  __syncthreads();
  for (int j = start + t; j < endv; j += 256) {
    uint2 p = pairs[j];
    int pos = cbase + atomicAdd(&cur[(int)p.x - base_n], 1);
    unsigned int pk = p.y;
    unsigned int idx17 = pk >> 17;
    csr0[pos] = idx17 << 7;                 // bf16 M0 rows: 128 B
    csr1[pos] = ((pk & 0x1FFFFu) << 8) | (idx17 & 15u);
  }
  __syncthreads();
  for (int j = myc; j < myp; ++j) {  // sentinel pads (at most 7 per node)
    int pos = cbase + excl + j;
    csr0[pos] = (unsigned int)(1904 << 7);
    csr1[pos] = ((unsigned int)NN) << 8;
  }
}

// ---- aggregation layer 0: wave per node; bf16 M0, two edges per gather
// instruction; mask-free (sentinel pads); shfl_xor(32) merge.
__global__ __launch_bounds__(256) void k_agg0(
    const int* __restrict__ x_idx, const float* __restrict__ atom,
    const unsigned short* __restrict__ M0, const int* __restrict__ offs,
    const int* __restrict__ cnts,
    const unsigned int* __restrict__ csr0, unsigned short* __restrict__ h0) {
  int t = threadIdx.x, lane = t & 63;
  int half = lane >> 5, c = lane & 31;
  int n = __builtin_amdgcn_readfirstlane(blockIdx.x * 4 + (t >> 6));
  if (n >= NN) return;
  int s = offs[n];
  int ep = s + ((cnts[n] + 7) & ~7);
  const char* Mb = (const char*)M0;
  unsigned int voff = (unsigned int)c * 4u;
  floatx2 acc; acc.x = 0.f; acc.y = 0.f;
  if (half == 0) {   // self term: h = x + agg
    float2 sv = *(const float2*)((const char*)atom +
                                 ((size_t)(unsigned)x_idx[n] << 8) + (size_t)c * 8u);
    acc.x = sv.x; acc.y = sv.y;
  }
  for (int i = s; i < ep; i += 8) {
    unsigned int a0 = csr0[i + 0], b0 = csr0[i + 1];
    unsigned int a1 = csr0[i + 2], b1 = csr0[i + 3];
    unsigned int a2 = csr0[i + 4], b2 = csr0[i + 5];
    unsigned int a3 = csr0[i + 6], b3 = csr0[i + 7];
    unsigned int q0 = half ? b0 : a0, q1 = half ? b1 : a1;
    unsigned int q2 = half ? b2 : a2, q3 = half ? b3 : a3;
    unsigned int v0 = *(const unsigned int*)(Mb + q0 + voff);
    unsigned int v1 = *(const unsigned int*)(Mb + q1 + voff);
    unsigned int v2 = *(const unsigned int*)(Mb + q2 + voff);
    unsigned int v3 = *(const unsigned int*)(Mb + q3 + voff);
    acc = acc + unpk(v0);
    acc = acc + unpk(v1);
    acc = acc + unpk(v2);
    acc = acc + unpk(v3);
  }
  float ax = acc.x + __shfl_xor(acc.x, 32);
  float ay = acc.y + __shfl_xor(acc.y, 32);
  if (half == 0) {
    unsigned int o = (unsigned int)f2bf(ax) | ((unsigned int)f2bf(ay) << 16);
    *(unsigned int*)(h0 + (size_t)n * 64 + c * 2) = o;
  }
}

// ---- aggregation layer 1: wave per node (full 256 B row per gather),
// mask-free (sentinel -inf pads); et1 in LDS, 8-deep load batches.
__global__ __launch_bounds__(256) void k_agg1(
    const unsigned short* __restrict__ x1, const float* __restrict__ et1,
    const int* __restrict__ offs, const int* __restrict__ cnts,
    const unsigned int* __restrict__ csr1, unsigned short* __restrict__ h1) {
  __shared__ float etl[2048];      // 16 rows x 128 ch, 8 KB
  int t = threadIdx.x;
#pragma unroll
  for (int k = 0; k < 8; ++k) etl[k * 256 + t] = et1[k * 256 + t];
  __syncthreads();
  int lane = t & 63;
  int n = __builtin_amdgcn_readfirstlane(blockIdx.x * 4 + (t >> 6));
  if (n >= NN) return;
  int s = offs[n];
  int ep = s + ((cnts[n] + 7) & ~7);
  const char* xb = (const char*)x1;
  unsigned int voff = (unsigned int)lane * 4u;
  const char* etb = (const char*)etl + (size_t)lane * 8u;
  unsigned int xv = *(const unsigned int*)(xb + ((size_t)(unsigned)n << 8) + voff);
  floatx2 acc = unpk(xv);
  floatx2 zero2; zero2.x = 0.f; zero2.y = 0.f;
  for (int i = s; i < ep; i += 8) {
    unsigned int q0 = csr1[i + 0], q1 = csr1[i + 1], q2 = csr1[i + 2], q3 = csr1[i + 3];
    unsigned int q4 = csr1[i + 4], q5 = csr1[i + 5], q6 = csr1[i + 6], q7 = csr1[i + 7];
    unsigned int v0 = *(const unsigned int*)(xb + ((q0 & 0xFFFFFF00u) | voff));
    unsigned int v1 = *(const unsigned int*)(xb + ((q1 & 0xFFFFFF00u) | voff));
    unsigned int v2 = *(const unsigned int*)(xb + ((q2 & 0xFFFFFF00u) | voff));
    unsigned int v3 = *(const unsigned int*)(xb + ((q3 & 0xFFFFFF00u) | voff));
    unsigned int v4 = *(const unsigned int*)(xb + ((q4 & 0xFFFFFF00u) | voff));
    unsigned int v5 = *(const unsigned int*)(xb + ((q5 & 0xFFFFFF00u) | voff));
    unsigned int v6 = *(const unsigned int*)(xb + ((q6 & 0xFFFFFF00u) | voff));
    unsigned int v7 = *(const unsigned int*)(xb + ((q7 & 0xFFFFFF00u) | voff));
    floatx2 e0 = *(const floatx2*)(etb + ((q0 & 15u) << 9));
    floatx2 e1 = *(const floatx2*)(etb + ((q1 & 15u) << 9));
    floatx2 e2 = *(const floatx2*)(etb + ((q2 & 15u) << 9));
    floatx2 e3 = *(const floatx2*)(etb + ((q3 & 15u) << 9));
    floatx2 e4 = *(const floatx2*)(etb + ((q4 & 15u) << 9));
    floatx2 e5 = *(const floatx2*)(etb + ((q5 & 15u) << 9));
    floatx2 e6 = *(const floatx2*)(etb + ((q6 & 15u) << 9));
    floatx2 e7 = *(const floatx2*)(etb + ((q7 & 15u) << 9));
    acc = acc + __builtin_elementwise_max(unpk(v0) + e0, zero2);
    acc = acc + __builtin_elementwise_max(unpk(v1) + e1, zero2);
    acc = acc + __builtin_elementwise_max(unpk(v2) + e2, zero2);
    acc = acc + __builtin_elementwise_max(unpk(v3) + e3, zero2);
    acc = acc + __builtin_elementwise_max(unpk(v4) + e4, zero2);
    acc = acc + __builtin_elementwise_max(unpk(v5) + e5, zero2);
    acc = acc + __builtin_elementwise_max(unpk(v6) + e6, zero2);
    acc = acc + __builtin_elementwise_max(unpk(v7) + e7, zero2);
  }
  unsigned int o = (unsigned int)f2bf(acc.x) | ((unsigned int)f2bf(acc.y) << 16);
  *(unsigned int*)(h1 + (size_t)n * 128 + lane * 2) = o;
}

// ---- double-GEMM MLP: 128 rows/block (2 tiles), w2 in LDS, one barrier,
// wave-private tls, coalesced dwordx4 stores.
template <int K1>
__global__ __launch_bounds__(256) void k_mlp_t(
    const unsigned short* __restrict__ in,
    const unsigned short* __restrict__ w1z, const float* __restrict__ b1,
    const unsigned short* __restrict__ w2z, const float* __restrict__ b2,
    unsigned short* __restrict__ outb, int N) {
  __shared__ unsigned short tls[4][16][136];   // wave-private mid/out tile
  __shared__ unsigned short b2s[16384];        // 32 KB staged w2 frags
  int t = threadIdx.x;
  int lane = t & 63;
  int wave = t >> 6;
  int rlo = lane & 15, quad = lane >> 4;

#pragma unroll
  for (int k = 0; k < 8; ++k)
    *(shortx8*)&b2s[(k * 256 + t) * 8] = *(const shortx8*)&w2z[(k * 256 + t) * 8];

  float bm1[8], bm2[8];
#pragma unroll
  for (int ct = 0; ct < 8; ++ct) { bm1[ct] = b1[ct * 16 + rlo]; bm2[ct] = b2[ct * 16 + rlo]; }

  __syncthreads();   // b2s ready (only barrier)

#pragma unroll
  for (int t2 = 0; t2 < 2; ++t2) {
    int row0 = blockIdx.x * 128 + t2 * 64 + wave * 16;
    int arow = row0 + rlo;

    floatx4 acc[8];
#pragma unroll
    for (int ct = 0; ct < 8; ++ct) { acc[ct][0]=0.f; acc[ct][1]=0.f; acc[ct][2]=0.f; acc[ct][3]=0.f; }
    const int NS = K1 >> 5;
#pragma unroll
    for (int s = 0; s < NS; ++s) {
      shortx8 a = {0,0,0,0,0,0,0,0};
      if (arow < N) a = *(const shortx8*)(in + (size_t)arow * K1 + s * 32 + quad * 8);
      const unsigned short* wp = w1z + ((size_t)(s * 8) * 64 + lane) * 8;
#pragma unroll
      for (int ct = 0; ct < 8; ++ct) {
        shortx8 b = *(const shortx8*)(wp + ct * 512);
        acc[ct] = __builtin_amdgcn_mfma_f32_16x16x32_bf16(a, b, acc[ct], 0, 0, 0);
      }
    }
#pragma unroll
    for (int ct = 0; ct < 8; ++ct) {
#pragma unroll
      for (int r = 0; r < 4; ++r) {
        float v = elu_fast(acc[ct][r] + bm1[ct]);
        tls[wave][quad * 4 + r][ct * 16 + rlo] = f2bf(v);
      }
    }
    // no barrier: tls[wave] is wave-private; DS ops are wave-ordered.

    floatx4 acc2[8];
#pragma unroll
    for (int ct = 0; ct < 8; ++ct) { acc2[ct][0]=0.f; acc2[ct][1]=0.f; acc2[ct][2]=0.f; acc2[ct][3]=0.f; }
#pragma unroll
    for (int s = 0; s < 4; ++s) {
      shortx8 a = *(const shortx8*)&tls[wave][rlo][s * 32 + quad * 8];
      const unsigned short* wp = &b2s[((s * 8) * 64 + lane) * 8];
#pragma unroll
      for (int ct = 0; ct < 8; ++ct) {
        shortx8 b = *(const shortx8*)(wp + ct * 512);
        acc2[ct] = __builtin_amdgcn_mfma_f32_16x16x32_bf16(a, b, acc2[ct], 0, 0, 0);
      }
    }
#pragma unroll
    for (int ct = 0; ct < 8; ++ct) {
#pragma unroll
      for (int r = 0; r < 4; ++r) {
        float v = elu_fast(acc2[ct][r] + bm2[ct]);
        tls[wave][quad * 4 + r][ct * 16 + rlo] = f2bf(v);
      }
    }
    int srow = lane >> 2;           // 0..15
    int schunk = lane & 3;          // 0..3
    int grow = row0 + srow;
#pragma unroll
    for (int k = 0; k < 4; ++k) {
      int ch = schunk + k * 4;      // 16B chunk (8 cols)
      if (grow < N)
        *(shortx8*)(outb + (size_t)grow * 128 + ch * 8) =
            *(const shortx8*)&tls[wave][srow][ch * 8];
    }
  }
}

// ---- pooling (R7-proven): wave per 32-node chunk, lane = 2 channels.
__global__ __launch_bounds__(256) void k_pool(
    const unsigned short* __restrict__ x2, const int* __restrict__ batch,
    float* __restrict__ hgf) {
  int gt = blockIdx.x * 256 + threadIdx.x;
  int chunk = gt >> 6, lane = gt & 63;
  int n0 = chunk * 32;
  if (n0 >= NN) return;
  int nend = n0 + 32; if (nend > NN) nend = NN;
  float ax = 0.f, ay = 0.f;
  const unsigned short* xp = x2 + lane * 2;
  int gcur = batch[n0];
  for (int n = n0; n < nend; ++n) {
    int g = batch[n];
    if (g != gcur) {
      atomicAdd(&hgf[gcur * 128 + lane * 2], ax);
      atomicAdd(&hgf[gcur * 128 + lane * 2 + 1], ay);
      ax = 0.f; ay = 0.f; gcur = g;
    }
    unsigned int v = *(const unsigned int*)(xp + (size_t)n * 128);
    ax += bf2f((unsigned short)(v & 0xFFFF));
    ay += bf2f((unsigned short)(v >> 16));
  }
  atomicAdd(&hgf[gcur * 128 + lane * 2], ax);
  atomicAdd(&hgf[gcur * 128 + lane * 2 + 1], ay);
}

// ---- head MLP: A rows fp32 (pooled), out fp32 = (relu(in@l1+b))@l2+b
__global__ void k_head(const float* __restrict__ in,
                       const unsigned short* __restrict__ w1z, const float* __restrict__ b1,
                       const unsigned short* __restrict__ w2z, const float* __restrict__ b2,
                       float* __restrict__ outf, int N) {
  __shared__ unsigned short tls[4][16][136];
  int lane = threadIdx.x & 63;
  int wave = threadIdx.x >> 6;
  int row0 = blockIdx.x * 64 + wave * 16;
  int rlo = lane & 15, quad = lane >> 4;
  int arow = row0 + rlo;
  floatx4 acc[8];
#pragma unroll
  for (int ct = 0; ct < 8; ++ct) { acc[ct][0]=0.f; acc[ct][1]=0.f; acc[ct][2]=0.f; acc[ct][3]=0.f; }
#pragma unroll
  for (int s = 0; s < 4; ++s) {
    shortx8 a = {0,0,0,0,0,0,0,0};
    if (arow < N) {
      const float* rp = in + (size_t)arow * 128 + s * 32 + quad * 8;
      float4 f0 = *(const float4*)rp;
      float4 f1 = *(const float4*)(rp + 4);
      a[0] = (short)f2bf(f0.x); a[1] = (short)f2bf(f0.y);
      a[2] = (short)f2bf(f0.z); a[3] = (short)f2bf(f0.w);
      a[4] = (short)f2bf(f1.x); a[5] = (short)f2bf(f1.y);
      a[6] = (short)f2bf(f1.z); a[7] = (short)f2bf(f1.w);
    }
    const unsigned short* wp = w1z + ((size_t)(s * 8) * 64 + lane) * 8;
#pragma unroll
    for (int ct = 0; ct < 8; ++ct) {
      shortx8 b = *(const shortx8*)(wp + ct * 512);
      acc[ct] = __builtin_amdgcn_mfma_f32_16x16x32_bf16(a, b, acc[ct], 0, 0, 0);
    }
  }
#pragma unroll
  for (int ct = 0; ct < 8; ++ct) {
    float bm = b1[ct * 16 + rlo];
#pragma unroll
    for (int r = 0; r < 4; ++r) {
      float v = acc[ct][r] + bm;
      v = v > 0.f ? v : 0.f;  // relu
      tls[wave][quad * 4 + r][ct * 16 + rlo] = f2bf(v);
    }
  }
  __syncthreads();
  floatx4 acc2[8];
#pragma unroll
  for (int ct = 0; ct < 8; ++ct) { acc2[ct][0]=0.f; acc2[ct][1]=0.f; acc2[ct][2]=0.f; acc2[ct][3]=0.f; }
#pragma unroll
  for (int s = 0; s < 4; ++s) {
    shortx8 a = *(const shortx8*)&tls[wave][rlo][s * 32 + quad * 8];
    const unsigned short* wp = w2z + ((size_t)(s * 8) * 64 + lane) * 8;
#pragma unroll
    for (int ct = 0; ct < 8; ++ct) {
      shortx8 b = *(const shortx8*)(wp + ct * 512);
      acc2[ct] = __builtin_amdgcn_mfma_f32_16x16x32_bf16(a, b, acc2[ct], 0, 0, 0);
    }
  }
#pragma unroll
  for (int ct = 0; ct < 8; ++ct) {
    float bm = b2[ct * 16 + rlo];
#pragma unroll
    for (int r = 0; r < 4; ++r) {
      int rr = row0 + quad * 4 + r;
      if (rr < N) outf[(size_t)rr * 128 + ct * 16 + rlo] = acc2[ct][r] + bm;
    }
  }
}

extern "C" void kernel_launch(void* const* d_in, const int* in_sizes, int n_in,
                              void* d_out, int out_size, void* d_ws, size_t ws_size,
                              hipStream_t stream) {
  const int* x_idx  = (const int*)d_in[0];
  const int* e_src  = (const int*)d_in[1];
  const int* e_dst  = e_src + NE;
  const int* e_attr = (const int*)d_in[2];
  const int* batch  = (const int*)d_in[3];
  const float* atom = (const float*)d_in[4];
  const float* bond = (const float*)d_in[5];
  const float* we0  = (const float*)d_in[6];
  const float* be0  = (const float*)d_in[7];
  const float* w1_0 = (const float*)d_in[8];
  const float* b1_0 = (const float*)d_in[9];
  const float* w2_0 = (const float*)d_in[10];
  const float* b2_0 = (const float*)d_in[11];
  const float* we1  = (const float*)d_in[12];
  const float* be1  = (const float*)d_in[13];
  const float* w1_1 = (const float*)d_in[14];
  const float* b1_1 = (const float*)d_in[15];
  const float* w2_1 = (const float*)d_in[16];
  const float* b2_1 = (const float*)d_in[17];
  const float* l1w  = (const float*)d_in[18];
  const float* l1b  = (const float*)d_in[19];
  const float* l2w  = (const float*)d_in[20];
  const float* l2b  = (const float*)d_in[21];

  char* ws = (char*)d_ws;
  size_t off = 0;
  auto alloc = [&](size_t bytes) -> void* {
    void* p = ws + off;
    off = (off + bytes + 255) & ~(size_t)255;
    return p;
  };
  int* bcursor = (int*)alloc((size_t)NB * 4);
  int* offs    = (int*)alloc((size_t)NN * 4);
  int* cnts    = (int*)alloc((size_t)NN * 4);
  float* et1   = (float*)alloc(16 * 128 * 4);
  unsigned short* M0 = (unsigned short*)alloc((size_t)1905 * 64 * 2);  // bf16 + zero row
  float* hgf   = (float*)alloc((size_t)NG * 128 * 4);
  unsigned short* w1_0z = (unsigned short*)alloc(64 * 128 * 2);
  unsigned short* w2_0z = (unsigned short*)alloc(128 * 128 * 2);
  unsigned short* w1_1z = (unsigned short*)alloc(128 * 128 * 2);
  unsigned short* w2_1z = (unsigned short*)alloc(128 * 128 * 2);
  unsigned short* l1z   = (unsigned short*)alloc(128 * 128 * 2);
  unsigned short* l2z   = (unsigned short*)alloc(128 * 128 * 2);
  uint2* pairs = (uint2*)alloc((size_t)NB * PS * 8);       // dead after k_fine
  unsigned int* csr0 = (unsigned int*)alloc((size_t)NB * CS * 4);
  unsigned int* csr1 = (unsigned int*)alloc((size_t)NB * CS * 4);
  unsigned short* x1 = (unsigned short*)alloc((size_t)(NN + 1) * 128 * 2); // + -inf row
  unsigned short* h1 = (unsigned short*)alloc((size_t)NN * 128 * 2);
  unsigned short* h0 = (unsigned short*)pairs;  // 12.8 MB alias: pairs dead before agg0
  unsigned short* x2 = h1;  // in-place mlp1 (wave reads own rows before writing)

  k_prep<<<885, 256, 0, stream>>>(bond, we0, be0, we1, be1, atom, et1, M0, hgf, bcursor,
                                  x1,
                                  w1_0, w2_0, w1_1, w2_1, l1w, l2w,
                                  w1_0z, w2_0z, w1_1z, w2_1z, l1z, l2z);
  k_bin<<<(NE + 4095) / 4096, 256, 0, stream>>>(e_src, e_dst, e_attr, x_idx, bcursor, pairs);
  k_fine<<<NB, 256, 0, stream>>>(pairs, bcursor, offs, cnts, csr0, csr1);
  k_agg0<<<NN / 4, 256, 0, stream>>>(x_idx, atom, M0, offs, cnts, csr0, h0);
  k_mlp_t<64><<<(NN + 127) / 128, 256, 0, stream>>>(h0, w1_0z, b1_0, w2_0z, b2_0, x1, NN);
  k_agg1<<<NN / 4, 256, 0, stream>>>(x1, et1, offs, cnts, csr1, h1);
  k_mlp_t<128><<<(NN + 127) / 128, 256, 0, stream>>>(h1, w1_1z, b1_1, w2_1z, b2_1, x2, NN);
  k_pool<<<(((NN + 31) / 32) * 64 + 255) / 256, 256, 0, stream>>>(x2, batch, hgf);
  k_head<<<(NG + 63) / 64, 256, 0, stream>>>(hgf, l1z, l1b, l2z, l2b, (float*)d_out, NG);
}